// Round 6
// baseline (337.477 us; speedup 1.0000x reference)
//
#include <hip/hip_runtime.h>
#include <hip/hip_bf16.h>

using bf16x8 = __attribute__((ext_vector_type(8))) short;
using f32x4  = __attribute__((ext_vector_type(4))) float;

static constexpr int NN = 2048;   // nodes
static constexpr int NB = 32;     // batch
static constexpr int NC = 32;     // channels (C1 == C2)

__device__ __forceinline__ unsigned short f2bf(float f) {
    unsigned int u = __float_as_uint(f);
    u += 0x7FFFu + ((u >> 16) & 1u);   // round-to-nearest-even
    return (unsigned short)(u >> 16);
}

// ---------------------------------------------------------------------------
// Projection: XWt[b][c][m] = bf16( sum_f X[b][m][f] * W[f][c] )   (no bias/relu)
// grid = (NN/256, NB), block = 256. One thread per node-row m.
// ---------------------------------------------------------------------------
template<int INCH>
__global__ void proj_kernel(const float* __restrict__ X, const float* __restrict__ W,
                            unsigned short* __restrict__ XWt)
{
    __shared__ float wlds[INCH * NC];
    const int b = blockIdx.y;
    const int m = blockIdx.x * 256 + threadIdx.x;
    for (int i = threadIdx.x; i < INCH * NC; i += 256) wlds[i] = W[i];
    __syncthreads();

    const float* xrow = X + ((size_t)b * NN + m) * INCH;
    float acc[NC];
#pragma unroll
    for (int c = 0; c < NC; ++c) acc[c] = 0.f;

    for (int f = 0; f < INCH; f += 4) {
        const float4 v = *reinterpret_cast<const float4*>(xrow + f);
        const float xv[4] = {v.x, v.y, v.z, v.w};
#pragma unroll
        for (int j = 0; j < 4; ++j) {
#pragma unroll
            for (int c = 0; c < NC; ++c)
                acc[c] += xv[j] * wlds[(f + j) * NC + c];
        }
    }

    unsigned short* outp = XWt + (size_t)b * NC * NN + m;
#pragma unroll
    for (int c = 0; c < NC; ++c) outp[(size_t)c * NN] = f2bf(acc[c]);
}

// ---------------------------------------------------------------------------
// LDS-staged GCN GEMM.  Per block: 64 output rows, full K in 64-wide chunks.
// A chunk 64x64 fp32 (16KB) + B chunk 32x64 bf16 (4KB), double-buffered (40KB).
// Staging is reg-staged with LANE-LINEAR global addresses (lane i -> base+16i,
// 256B runs per 16 lanes) — the previous direct-MFMA structure made
// consecutive lanes read 8KB apart (16-line scatter per instr), the one
// invariant across five BW-null rounds.
// LDS XOR seg-swizzle: A pos = seg^(row&15), B pos = seg^(row&7) -> 2-way
// bank aliasing only (free, m136) for both ds_write_b128 and ds_read_b128.
// FUSE=true : epilogue computes xwt2 = relu(acc+b1) @ W2 via LDS (layer1+proj2)
// FUSE=false: epilogue relu(acc+b2), column-sum -> atomicAdd pooled (layer2+pool)
// ---------------------------------------------------------------------------
template<bool FUSE>
__global__ __launch_bounds__(256, 4)
void gcn_gemm_lds(const float* __restrict__ A, const unsigned short* __restrict__ Bt,
                  const float* __restrict__ bias, const float* __restrict__ W2,
                  unsigned short* __restrict__ XWt2, float* __restrict__ pooled)
{
    __shared__ float          Abuf[2][64 * 64];   // 16 KB x2, seg-swizzled [row][seg^row]
    __shared__ unsigned short Bbuf[2][32 * 64];   // 4 KB x2, seg-swizzled

    const int b    = blockIdx.y;
    const int t    = threadIdx.x;
    const int wave = t >> 6, lane = t & 63;
    const int lr   = lane & 15, kg = lane >> 4;
    const int brow = blockIdx.x * 64;

    // staging geometry (lane-linear global, swizzle folded into source seg)
    const int arow_l = t >> 4;                  // sub-row 0..15 within 16-row group
    const int aseg   = (t & 15) ^ arow_l;       // source seg (16B units) for A
    const int brows  = t >> 3;                  // B row 0..31
    const int bseg   = (t & 7) ^ (brows & 7);   // source seg for B

    const float*          Ab = A  + ((size_t)b * NN + brow) * NN;
    const unsigned short* Bb = Bt + (size_t)b * NC * NN;

    float4 areg[4]; bf16x8 breg;
    auto ldregs = [&](int kc) {
#pragma unroll
        for (int i = 0; i < 4; ++i)
            areg[i] = *reinterpret_cast<const float4*>(
                Ab + (size_t)(i * 16 + arow_l) * NN + kc * 64 + aseg * 4);
        breg = *reinterpret_cast<const bf16x8*>(
                Bb + (size_t)brows * NN + kc * 64 + bseg * 8);
    };
    auto dswrite = [&](int buf) {
#pragma unroll
        for (int i = 0; i < 4; ++i)
            *reinterpret_cast<float4*>(&Abuf[buf][(i * 256 + t) * 4]) = areg[i];
        *reinterpret_cast<bf16x8*>(&Bbuf[buf][t * 8]) = breg;
    };

    f32x4 acc0 = {0.f, 0.f, 0.f, 0.f};
    f32x4 acc1 = {0.f, 0.f, 0.f, 0.f};
    union ABf { bf16x8 v; __hip_bfloat16 e[8]; };

    ldregs(0); dswrite(0); __syncthreads();

    const int r = wave * 16 + lr;    // A row this lane consumes (also its swizzle key)
    int cur = 0;
    for (int kc = 0; kc < NN / 64; ++kc) {
        if (kc + 1 < NN / 64) ldregs(kc + 1);   // prefetch next chunk (hidden under MFMA)
#pragma unroll
        for (int k2 = 0; k2 < 2; ++k2) {
            const int s0 = k2 * 8 + kg * 2;
            const float4 a0 = *reinterpret_cast<const float4*>(
                &Abuf[cur][r * 64 + ((s0    ) ^ lr) * 4]);
            const float4 a1 = *reinterpret_cast<const float4*>(
                &Abuf[cur][r * 64 + ((s0 + 1) ^ lr) * 4]);
            const int sb = (k2 * 4 + kg) ^ (lr & 7);
            const bf16x8 bv0 = *reinterpret_cast<const bf16x8*>(
                &Bbuf[cur][lr        * 64 + sb * 8]);
            const bf16x8 bv1 = *reinterpret_cast<const bf16x8*>(
                &Bbuf[cur][(lr + 16) * 64 + sb * 8]);

            ABf af;
            af.e[0] = __float2bfloat16(a0.x); af.e[1] = __float2bfloat16(a0.y);
            af.e[2] = __float2bfloat16(a0.z); af.e[3] = __float2bfloat16(a0.w);
            af.e[4] = __float2bfloat16(a1.x); af.e[5] = __float2bfloat16(a1.y);
            af.e[6] = __float2bfloat16(a1.z); af.e[7] = __float2bfloat16(a1.w);

            acc0 = __builtin_amdgcn_mfma_f32_16x16x32_bf16(af.v, bv0, acc0, 0, 0, 0);
            acc1 = __builtin_amdgcn_mfma_f32_16x16x32_bf16(af.v, bv1, acc1, 0, 0, 0);
        }
        if (kc + 1 < NN / 64) dswrite(cur ^ 1);
        __syncthreads();
        cur ^= 1;
    }

    const float b0  = bias[lr];
    const float b1v = bias[lr + 16];

    if constexpr (FUSE) {
        // h tile -> LDS (reuse Abuf[0]), W2 -> LDS (reuse Bbuf[0]); then per-thread
        // projection of one row into 8 output channels of xwt2.
        float* hl  = &Abuf[0][0];                              // 64*33 floats
        float* w2l = reinterpret_cast<float*>(&Bbuf[0][0]);    // 1024 floats
#pragma unroll
        for (int j = 0; j < 4; ++j) {
            const int rr = wave * 16 + kg * 4 + j;
            hl[rr * 33 + lr]      = fmaxf(acc0[j] + b0,  0.f);
            hl[rr * 33 + lr + 16] = fmaxf(acc1[j] + b1v, 0.f);
        }
        *reinterpret_cast<float4*>(&w2l[t * 4]) =
            *reinterpret_cast<const float4*>(&W2[t * 4]);
        __syncthreads();

        const int m  = t >> 2;          // row 0..63
        const int c0 = (t & 3) * 8;     // output channel base
        float o[8] = {0.f, 0.f, 0.f, 0.f, 0.f, 0.f, 0.f, 0.f};
#pragma unroll
        for (int c = 0; c < 32; ++c) {
            const float hv = hl[m * 33 + c];
#pragma unroll
            for (int i = 0; i < 8; ++i) o[i] += hv * w2l[c * 32 + c0 + i];
        }
        unsigned short* op = XWt2 + (size_t)b * NC * NN + brow + m;
#pragma unroll
        for (int i = 0; i < 8; ++i) op[(size_t)(c0 + i) * NN] = f2bf(o[i]);
    } else {
        float s0 = 0.f, s1 = 0.f;
#pragma unroll
        for (int j = 0; j < 4; ++j) {
            s0 += fmaxf(acc0[j] + b0,  0.f);
            s1 += fmaxf(acc1[j] + b1v, 0.f);
        }
        s0 += __shfl_xor(s0, 16); s0 += __shfl_xor(s0, 32);
        s1 += __shfl_xor(s1, 16); s1 += __shfl_xor(s1, 32);
        if (kg == 0) {
            atomicAdd(&pooled[b * NC + lr],      s0);
            atomicAdd(&pooled[b * NC + 16 + lr], s1);
        }
    }
}

// ---------------------------------------------------------------------------
// FC head: out[b] = sum_h relu(pooled[b,:] @ Wf1[:,h] + bf1[h]) * Wf2[h] + bf2
// ---------------------------------------------------------------------------
__global__ void head_kernel(const float* __restrict__ pooled,
                            const float* __restrict__ Wf1, const float* __restrict__ bf1,
                            const float* __restrict__ Wf2, const float* __restrict__ bf2,
                            float* __restrict__ out)
{
    const int b = blockIdx.x;
    const int h = threadIdx.x;   // 0..511

    float dot = 0.f;
#pragma unroll
    for (int c = 0; c < NC; ++c)
        dot += pooled[b * NC + c] * Wf1[c * 512 + h];

    const float v = fmaxf(dot + bf1[h], 0.f);
    float part    = v * Wf2[h];

#pragma unroll
    for (int off = 32; off >= 1; off >>= 1)
        part += __shfl_xor(part, off);

    __shared__ float red[8];
    if ((threadIdx.x & 63) == 0) red[threadIdx.x >> 6] = part;
    __syncthreads();
    if (threadIdx.x == 0) {
        float s = 0.f;
#pragma unroll
        for (int i = 0; i < 8; ++i) s += red[i];
        out[b] = s + bf2[0];
    }
}

// ---------------------------------------------------------------------------
extern "C" void kernel_launch(void* const* d_in, const int* in_sizes, int n_in,
                              void* d_out, int out_size, void* d_ws, size_t ws_size,
                              hipStream_t stream)
{
    const float* x   = (const float*)d_in[0];
    const float* a   = (const float*)d_in[1];
    const float* W1  = (const float*)d_in[2];
    const float* b1  = (const float*)d_in[3];
    const float* W2  = (const float*)d_in[4];
    const float* b2  = (const float*)d_in[5];
    const float* Wf1 = (const float*)d_in[6];
    const float* bf1 = (const float*)d_in[7];
    const float* Wf2 = (const float*)d_in[8];
    const float* bf2 = (const float*)d_in[9];
    float* out = (float*)d_out;

    char* ws = (char*)d_ws;
    unsigned short* xwt1   = (unsigned short*)(ws);                 // 4 MB [b][c][m] bf16
    unsigned short* xwt2   = (unsigned short*)(ws + (4ull << 20));  // 4 MB [b][c][m] bf16
    float*          pooled = (float*)(ws + (8ull << 20));           // 4 KB [b][c] fp32

    hipMemsetAsync(pooled, 0, NB * NC * sizeof(float), stream);

    proj_kernel<64><<<dim3(NN / 256, NB), 256, 0, stream>>>(x, W1, xwt1);

    // layer 1 GEMM + fused proj2 (h1 never touches HBM)
    gcn_gemm_lds<true><<<dim3(NN / 64, NB), 256, 0, stream>>>(
        a, xwt1, b1, W2, xwt2, nullptr);

    // layer 2 GEMM + global sum-pool
    gcn_gemm_lds<false><<<dim3(NN / 64, NB), 256, 0, stream>>>(
        a, xwt2, b2, nullptr, nullptr, pooled);

    head_kernel<<<dim3(NB), 512, 0, stream>>>(pooled, Wf1, bf1, Wf2, bf2, out);
}